// Round 2
// baseline (1483.894 us; speedup 1.0000x reference)
//
#include <hip/hip_runtime.h>

#define NN 50000
#define NE 800000

typedef __bf16 bf16_t;
typedef __bf16 bf16x8 __attribute__((ext_vector_type(8)));
typedef float f32x4 __attribute__((ext_vector_type(4)));

// ---- workspace layout (bytes) ----
#define W1A_OFF 0
#define W1A_B (256 * 256 * 2)
#define W1B_OFF (W1A_OFF + W1A_B)
#define W1B_B (128 * 256 * 2)
#define W2A_OFF (W1B_OFF + W1B_B)
#define W2A_B (256 * 384 * 2)
#define W2B_OFF (W2A_OFF + W2A_B)
#define W2B_B (128 * 256 * 2)
#define WEND (W2B_OFF + W2B_B)

#define NSCAN_BLOCKS ((NN + 255) / 256)
#define BASE_OFF WEND
#define BASE_B (((NN + 1 + 63) / 64) * 64 * 4)
#define BSUM_OFF (BASE_OFF + BASE_B)
#define BSUM_B (256 * 4)
#define OFF_OFF (BSUM_OFF + BSUM_B)
#define OFF_B (NN * 4)
#define CNT2_OFF (OFF_OFF + OFF_B)
#define CNT2_B (NN * 4)
#define PERM_OFF (CNT2_OFF + CNT2_B)
#define PERM_B (NE * 4)

// Convert W[k][n] (row-major fp32) -> Wt[n][k] bf16 (k contiguous).
__global__ __launch_bounds__(256) void transpose_bf16(
    const float* __restrict__ src, bf16_t* __restrict__ dst, int K, int Nn) {
  int idx = blockIdx.x * 256 + threadIdx.x;
  if (idx >= K * Nn) return;
  int n = idx / K;
  int k = idx - n * K;
  dst[idx] = (bf16_t)src[k * Nn + n];
}

// ================= CSR construction =================
__global__ __launch_bounds__(256) void hist_kernel(
    const int* __restrict__ ei, int* __restrict__ cnt) {
  int e = blockIdx.x * 256 + threadIdx.x;
  if (e < NE) atomicAdd(&cnt[ei[NE + e]], 1);
}

__global__ __launch_bounds__(256) void scan1(
    const int* __restrict__ cnt, int* __restrict__ base, int* __restrict__ bsum) {
  __shared__ int s[256];
  const int tid = threadIdx.x;
  const int g = blockIdx.x * 256 + tid;
  int v = (g < NN) ? cnt[g] : 0;
  s[tid] = v;
  __syncthreads();
#pragma unroll
  for (int o = 1; o < 256; o <<= 1) {
    int t = (tid >= o) ? s[tid - o] : 0;
    __syncthreads();
    s[tid] += t;
    __syncthreads();
  }
  if (g < NN) base[g] = s[tid] - v;
  if (tid == 255) bsum[blockIdx.x] = s[255];
}

__global__ __launch_bounds__(256) void scan2(int* __restrict__ bsum, int nb) {
  __shared__ int s[256];
  const int tid = threadIdx.x;
  int v = (tid < nb) ? bsum[tid] : 0;
  s[tid] = v;
  __syncthreads();
#pragma unroll
  for (int o = 1; o < 256; o <<= 1) {
    int t = (tid >= o) ? s[tid - o] : 0;
    __syncthreads();
    s[tid] += t;
    __syncthreads();
  }
  if (tid < nb) bsum[tid] = s[tid] - v;
}

__global__ __launch_bounds__(256) void scan3(
    int* __restrict__ base, const int* __restrict__ bsum, int* __restrict__ off) {
  int g = blockIdx.x * 256 + threadIdx.x;
  if (g < NN) {
    int b = base[g] + bsum[g >> 8];
    base[g] = b;
    off[g] = b;
  } else if (g == NN) {
    base[NN] = NE;
  }
}

__global__ __launch_bounds__(256) void slot_kernel(
    const int* __restrict__ ei, int* __restrict__ off, int* __restrict__ perm) {
  int e = blockIdx.x * 256 + threadIdx.x;
  if (e < NE) {
    int p = atomicAdd(&off[ei[NE + e]], 1);
    perm[p] = e;
  }
}

// ================= fused GNN kernel =================
// One block = 32 destination nodes = contiguous CSR edge range.
// Edge-group loop: stage [x[src]|ea[e]] (K=256) -> MFMA vs full W1a
// (+bias,ReLU in-reg) -> scatter bf16 tile to LDS -> owning threads
// accumulate per-node sums in registers. Then mean -> @W1b -> mlp2.
// No hid buffer, no P buffer: saves ~1.7 GB of intermediate traffic.
__global__ __launch_bounds__(256) void fused_gnn(
    const float* __restrict__ x, const float* __restrict__ ea,
    const float* __restrict__ u, const int* __restrict__ batch,
    const int* __restrict__ ei, const int* __restrict__ perm,
    const int* __restrict__ base,
    const bf16_t* __restrict__ Wt1a, const float* __restrict__ b1a,
    const bf16_t* __restrict__ Wt1b, const float* __restrict__ b1b,
    const bf16_t* __restrict__ Wt2a, const float* __restrict__ b2a,
    const bf16_t* __restrict__ Wt2b, const float* __restrict__ b2b,
    float* __restrict__ out) {
  // arena: edge phase uses Ain[64][264] (33792 B); node phase reuses the
  // same bytes as As[32][392] (12544 elems) -- barriers separate the uses.
  __shared__ __align__(16) bf16_t arena[64 * 264];
  bf16_t(*Ain)[264] = (bf16_t(*)[264])arena;
  bf16_t(*As)[392] = (bf16_t(*)[392])arena;
  __shared__ int bS[32], bE[32], rowS[64], eS[64];

  const int tid = threadIdx.x, lane = tid & 63, wave = tid >> 6;
  const int n0 = blockIdx.x * 32;

  if (tid < 32) {
    int n = n0 + tid;
    bS[tid] = (n < NN) ? base[n] : NE;
    bE[tid] = (n < NN) ? base[n + 1] : NE;
  }
  __syncthreads();
  const int jb = bS[0], je = bE[31];
  const int lr = lane & 15, lq = lane >> 4;
  const int n_off = wave * 64;  // edge-layer: wave owns 64 of 256 cols

  float bias1[4];
#pragma unroll
  for (int nt = 0; nt < 4; ++nt) bias1[nt] = b1a[n_off + nt * 16 + lr];

  // consume mapping: thread owns (node ci, col-block cq of 32 cols)
  const int ci = tid >> 3, cq = tid & 7;
  const int cjb = bS[ci], cje = bE[ci];
  float sum[32];
#pragma unroll
  for (int c = 0; c < 32; ++c) sum[c] = 0.f;

  // ---- edge-group loop ----
  for (int g0 = jb; g0 < je; g0 += 64) {
    if (tid < 64) {
      const int j = g0 + tid;
      const int e = perm[(j < je) ? j : (je - 1)];
      eS[tid] = e;
      rowS[tid] = ei[e];
    }
    __syncthreads();  // prev consume done reading Ain; indices visible

    // stage concat [x | ea] -> Ain bf16 (K=256)
    {
      const int c0 = (tid & 63) * 4;
      const int esub = tid >> 6;
#pragma unroll
      for (int it = 0; it < 16; ++it) {
        const int i = it * 4 + esub;
        float4 f;
        if (c0 < 128)
          f = *(const float4*)(x + (size_t)rowS[i] * 128 + c0);
        else
          f = *(const float4*)(ea + (size_t)eS[i] * 128 + (c0 - 128));
        union { bf16_t h[4]; uint2 u2; } pk;
        pk.h[0] = (bf16_t)f.x; pk.h[1] = (bf16_t)f.y;
        pk.h[2] = (bf16_t)f.z; pk.h[3] = (bf16_t)f.w;
        *(uint2*)&Ain[i][c0] = pk.u2;
      }
    }
    __syncthreads();

    // Q = concat @ W1a (full K=256); wave owns cols [n_off, n_off+64)
    f32x4 acc[4][4];
#pragma unroll
    for (int mt = 0; mt < 4; ++mt)
#pragma unroll
      for (int nt = 0; nt < 4; ++nt) acc[mt][nt] = (f32x4){0.f, 0.f, 0.f, 0.f};
#pragma unroll
    for (int ks = 0; ks < 8; ++ks) {
      const int k0 = ks * 32 + lq * 8;
      bf16x8 af[4], bv[4];
#pragma unroll
      for (int mt = 0; mt < 4; ++mt) af[mt] = *(const bf16x8*)&Ain[mt * 16 + lr][k0];
#pragma unroll
      for (int nt = 0; nt < 4; ++nt)
        bv[nt] = *(const bf16x8*)&Wt1a[(n_off + nt * 16 + lr) * 256 + k0];
#pragma unroll
      for (int mt = 0; mt < 4; ++mt)
#pragma unroll
        for (int nt = 0; nt < 4; ++nt)
          acc[mt][nt] = __builtin_amdgcn_mfma_f32_16x16x32_bf16(
              af[mt], bv[nt], acc[mt][nt], 0, 0, 0);
    }
    __syncthreads();  // Ain reads complete; safe to overwrite

    // scatter relu(Q + b1a) bf16 -> Ain (as Qs[64][0..255])
#pragma unroll
    for (int mt = 0; mt < 4; ++mt)
#pragma unroll
      for (int nt = 0; nt < 4; ++nt) {
        const int row = mt * 16 + lq * 4;
        const int colF = n_off + nt * 16 + lr;
#pragma unroll
        for (int r = 0; r < 4; ++r)
          Ain[row + r][colF] = (bf16_t)fmaxf(acc[mt][nt][r] + bias1[nt], 0.f);
      }
    __syncthreads();

    // consume: accumulate this group's rows into per-node sums
    {
      const int lo = (cjb > g0) ? cjb : g0;
      const int hi = (cje < g0 + 64) ? cje : (g0 + 64);
      for (int j = lo; j < hi; ++j) {
        const bf16x8* qp = (const bf16x8*)&Ain[j - g0][cq * 32];
#pragma unroll
        for (int v = 0; v < 4; ++v) {
          bf16x8 hv = qp[v];
#pragma unroll
          for (int c = 0; c < 8; ++c) sum[v * 8 + c] += (float)hv[c];
        }
      }
    }
    // no trailing barrier: next iteration's first barrier protects Ain
  }
  __syncthreads();  // all consume reads of arena done

  // A1 = mean -> As cols 0..255
  {
    const float inv = 1.0f / fmaxf((float)(cje - cjb), 1.0f);
#pragma unroll
    for (int c = 0; c < 32; c += 4) {
      union { bf16_t h[4]; uint2 u2; } pk;
      pk.h[0] = (bf16_t)(sum[c] * inv);
      pk.h[1] = (bf16_t)(sum[c + 1] * inv);
      pk.h[2] = (bf16_t)(sum[c + 2] * inv);
      pk.h[3] = (bf16_t)(sum[c + 3] * inv);
      *(uint2*)&As[ci][cq * 32 + c] = pk.u2;
    }
  }
  __syncthreads();

  // phase 2: agg = A1 @ W1b (+ b1b if nonempty). M=32, N=128, K=256.
  const int n2 = wave * 32;
  float bias1b[2];
#pragma unroll
  for (int nt = 0; nt < 2; ++nt) bias1b[nt] = b1b[n2 + nt * 16 + lr];
  f32x4 accB[2][2];
#pragma unroll
  for (int mt = 0; mt < 2; ++mt)
#pragma unroll
    for (int nt = 0; nt < 2; ++nt) accB[mt][nt] = (f32x4){0.f, 0.f, 0.f, 0.f};
#pragma unroll
  for (int ks = 0; ks < 8; ++ks) {
    const int k0 = ks * 32 + lq * 8;
    bf16x8 af[2], bv[2];
#pragma unroll
    for (int mt = 0; mt < 2; ++mt) af[mt] = *(const bf16x8*)&As[mt * 16 + lr][k0];
#pragma unroll
    for (int nt = 0; nt < 2; ++nt)
      bv[nt] = *(const bf16x8*)&Wt1b[(n2 + nt * 16 + lr) * 256 + k0];
#pragma unroll
    for (int mt = 0; mt < 2; ++mt)
#pragma unroll
      for (int nt = 0; nt < 2; ++nt)
        accB[mt][nt] = __builtin_amdgcn_mfma_f32_16x16x32_bf16(
            af[mt], bv[nt], accB[mt][nt], 0, 0, 0);
  }
  __syncthreads();

  // write agg -> As cols 128..255; stage x -> cols 0..127, u -> 256..383
#pragma unroll
  for (int mt = 0; mt < 2; ++mt)
#pragma unroll
    for (int nt = 0; nt < 2; ++nt) {
      const int colF = n2 + nt * 16 + lr;
#pragma unroll
      for (int r = 0; r < 4; ++r) {
        const int row = mt * 16 + lq * 4 + r;
        const float bb = (bE[row] > bS[row]) ? bias1b[nt] : 0.f;
        As[row][128 + colF] = (bf16_t)(accB[mt][nt][r] + bb);
      }
    }
  for (int v = tid; v < 32 * 32; v += 256) {
    const int i = v >> 5, c0 = (v & 31) * 4;
    const int n = n0 + i;
    float4 f = make_float4(0.f, 0.f, 0.f, 0.f);
    if (n < NN) f = *(const float4*)(x + (size_t)n * 128 + c0);
    union { bf16_t h[4]; uint2 u2; } pk;
    pk.h[0] = (bf16_t)f.x; pk.h[1] = (bf16_t)f.y;
    pk.h[2] = (bf16_t)f.z; pk.h[3] = (bf16_t)f.w;
    *(uint2*)&As[i][c0] = pk.u2;
  }
  for (int v = tid; v < 32 * 32; v += 256) {
    const int i = v >> 5, c0 = (v & 31) * 4;
    const int n = n0 + i;
    float4 f = make_float4(0.f, 0.f, 0.f, 0.f);
    if (n < NN) f = *(const float4*)(u + (size_t)batch[n] * 128 + c0);
    union { bf16_t h[4]; uint2 u2; } pk;
    pk.h[0] = (bf16_t)f.x; pk.h[1] = (bf16_t)f.y;
    pk.h[2] = (bf16_t)f.z; pk.h[3] = (bf16_t)f.w;
    *(uint2*)&As[i][256 + c0] = pk.u2;
  }
  __syncthreads();

  // phase 3: hidden = relu(z @ W2a + b2a). M=32, N=256, K=384.
  float bias2a[4];
#pragma unroll
  for (int nt = 0; nt < 4; ++nt) bias2a[nt] = b2a[n_off + nt * 16 + lr];
  f32x4 accC[2][4];
#pragma unroll
  for (int mt = 0; mt < 2; ++mt)
#pragma unroll
    for (int nt = 0; nt < 4; ++nt) accC[mt][nt] = (f32x4){0.f, 0.f, 0.f, 0.f};
#pragma unroll
  for (int ks = 0; ks < 12; ++ks) {
    const int k0 = ks * 32 + lq * 8;
    bf16x8 af[2], bv[4];
#pragma unroll
    for (int mt = 0; mt < 2; ++mt) af[mt] = *(const bf16x8*)&As[mt * 16 + lr][k0];
#pragma unroll
    for (int nt = 0; nt < 4; ++nt)
      bv[nt] = *(const bf16x8*)&Wt2a[(n_off + nt * 16 + lr) * 384 + k0];
#pragma unroll
    for (int mt = 0; mt < 2; ++mt)
#pragma unroll
      for (int nt = 0; nt < 4; ++nt)
        accC[mt][nt] = __builtin_amdgcn_mfma_f32_16x16x32_bf16(
            af[mt], bv[nt], accC[mt][nt], 0, 0, 0);
  }
  __syncthreads();
#pragma unroll
  for (int mt = 0; mt < 2; ++mt)
#pragma unroll
    for (int nt = 0; nt < 4; ++nt) {
      const int row = mt * 16 + lq * 4;
      const int colF = n_off + nt * 16 + lr;
#pragma unroll
      for (int r = 0; r < 4; ++r)
        As[row + r][colF] = (bf16_t)fmaxf(accC[mt][nt][r] + bias2a[nt], 0.f);
    }
  __syncthreads();

  // phase 4: out = hidden @ W2b + b2b. M=32, N=128, K=256.
  float bias2b[2];
#pragma unroll
  for (int nt = 0; nt < 2; ++nt) bias2b[nt] = b2b[n2 + nt * 16 + lr];
  f32x4 accD[2][2];
#pragma unroll
  for (int mt = 0; mt < 2; ++mt)
#pragma unroll
    for (int nt = 0; nt < 2; ++nt) accD[mt][nt] = (f32x4){0.f, 0.f, 0.f, 0.f};
#pragma unroll
  for (int ks = 0; ks < 8; ++ks) {
    const int k0 = ks * 32 + lq * 8;
    bf16x8 af[2], bv[2];
#pragma unroll
    for (int mt = 0; mt < 2; ++mt) af[mt] = *(const bf16x8*)&As[mt * 16 + lr][k0];
#pragma unroll
    for (int nt = 0; nt < 2; ++nt)
      bv[nt] = *(const bf16x8*)&Wt2b[(n2 + nt * 16 + lr) * 256 + k0];
#pragma unroll
    for (int mt = 0; mt < 2; ++mt)
#pragma unroll
      for (int nt = 0; nt < 2; ++nt)
        accD[mt][nt] = __builtin_amdgcn_mfma_f32_16x16x32_bf16(
            af[mt], bv[nt], accD[mt][nt], 0, 0, 0);
  }
#pragma unroll
  for (int mt = 0; mt < 2; ++mt)
#pragma unroll
    for (int nt = 0; nt < 2; ++nt) {
      const int colF = n2 + nt * 16 + lr;
#pragma unroll
      for (int r = 0; r < 4; ++r) {
        const int row = mt * 16 + lq * 4 + r;
        const int n = n0 + row;
        if (n < NN) out[(size_t)n * 128 + colF] = accD[mt][nt][r] + bias2b[nt];
      }
    }
}

extern "C" void kernel_launch(void* const* d_in, const int* in_sizes, int n_in,
                              void* d_out, int out_size, void* d_ws, size_t ws_size,
                              hipStream_t stream) {
  const float* x    = (const float*)d_in[0];
  const int*   ei   = (const int*)d_in[1];
  const float* ea   = (const float*)d_in[2];
  const float* u    = (const float*)d_in[3];
  const int*   batch= (const int*)d_in[4];
  const float* W1a  = (const float*)d_in[5];
  const float* b1a  = (const float*)d_in[6];
  const float* W1b  = (const float*)d_in[7];
  const float* b1b  = (const float*)d_in[8];
  const float* W2a  = (const float*)d_in[9];
  const float* b2a  = (const float*)d_in[10];
  const float* W2b  = (const float*)d_in[11];
  const float* b2b  = (const float*)d_in[12];

  char* ws = (char*)d_ws;
  bf16_t* w1a = (bf16_t*)(ws + W1A_OFF);
  bf16_t* w1b = (bf16_t*)(ws + W1B_OFF);
  bf16_t* w2a = (bf16_t*)(ws + W2A_OFF);
  bf16_t* w2b = (bf16_t*)(ws + W2B_OFF);

  transpose_bf16<<<256, 256, 0, stream>>>(W1a, w1a, 256, 256);
  transpose_bf16<<<128, 256, 0, stream>>>(W1b, w1b, 256, 128);
  transpose_bf16<<<384, 256, 0, stream>>>(W2a, w2a, 384, 256);
  transpose_bf16<<<128, 256, 0, stream>>>(W2b, w2b, 256, 128);

  int* base = (int*)(ws + BASE_OFF);
  int* bsum = (int*)(ws + BSUM_OFF);
  int* off  = (int*)(ws + OFF_OFF);
  int* cnt  = (int*)(ws + CNT2_OFF);
  int* perm = (int*)(ws + PERM_OFF);

  hipMemsetAsync(cnt, 0, CNT2_B, stream);
  hist_kernel<<<(NE + 255) / 256, 256, 0, stream>>>(ei, cnt);
  scan1<<<NSCAN_BLOCKS, 256, 0, stream>>>(cnt, base, bsum);
  scan2<<<1, 256, 0, stream>>>(bsum, NSCAN_BLOCKS);
  scan3<<<(NN + 256) / 256, 256, 0, stream>>>(base, bsum, off);
  slot_kernel<<<(NE + 255) / 256, 256, 0, stream>>>(ei, off, perm);

  fused_gnn<<<(NN + 31) / 32, 256, 0, stream>>>(
      x, ea, u, batch, ei, perm, base,
      w1a, b1a, w1b, b1b, w2a, b2a, w2b, b2b, (float*)d_out);
}

// Round 3
// 1107.877 us; speedup vs baseline: 1.3394x; 1.3394x over previous
//
#include <hip/hip_runtime.h>

#define NN 50000
#define NE 800000

typedef __bf16 bf16_t;
typedef __bf16 bf16x8 __attribute__((ext_vector_type(8)));
typedef float f32x4 __attribute__((ext_vector_type(4)));

// ---- workspace layout (bytes) ----
#define W1A_OFF 0
#define W1A_B (256 * 256 * 2)
#define W1B_OFF (W1A_OFF + W1A_B)
#define W1B_B (128 * 256 * 2)
#define W2A_OFF (W1B_OFF + W1B_B)
#define W2A_B (256 * 384 * 2)
#define W2B_OFF (W2A_OFF + W2A_B)
#define W2B_B (128 * 256 * 2)
#define WEND (W2B_OFF + W2B_B)

#define NSCAN_BLOCKS ((NN + 255) / 256)
#define BASE_OFF WEND
#define BASE_B (((NN + 1 + 63) / 64) * 64 * 4)
#define BSUM_OFF (BASE_OFF + BASE_B)
#define BSUM_B (256 * 4)
#define OFF_OFF (BSUM_OFF + BSUM_B)
#define OFF_B (NN * 4)
#define CNT2_OFF (OFF_OFF + OFF_B)
#define CNT2_B (NN * 4)
#define PERM_OFF (CNT2_OFF + CNT2_B)
#define PERM_B (NE * 4)
#define SRC2_OFF (PERM_OFF + PERM_B)
#define SRC2_B (NE * 4)
#define DST2_OFF (SRC2_OFF + SRC2_B)
#define DST2_B (NE * 4)
#define SUM_OFF ((size_t)(((DST2_OFF + DST2_B) + 255) / 256 * 256))
#define SUM_B ((size_t)NN * 256 * 4)

// Convert W[k][n] (row-major fp32) -> Wt[n][k] bf16 (k contiguous).
__global__ __launch_bounds__(256) void transpose_bf16(
    const float* __restrict__ src, bf16_t* __restrict__ dst, int K, int Nn) {
  int idx = blockIdx.x * 256 + threadIdx.x;
  if (idx >= K * Nn) return;
  int n = idx / K;
  int k = idx - n * K;
  dst[idx] = (bf16_t)src[k * Nn + n];
}

// ================= CSR construction =================
__global__ __launch_bounds__(256) void hist_kernel(
    const int* __restrict__ ei, int* __restrict__ cnt) {
  int e = blockIdx.x * 256 + threadIdx.x;
  if (e < NE) atomicAdd(&cnt[ei[NE + e]], 1);
}

__global__ __launch_bounds__(256) void scan1(
    const int* __restrict__ cnt, int* __restrict__ base, int* __restrict__ bsum) {
  __shared__ int s[256];
  const int tid = threadIdx.x;
  const int g = blockIdx.x * 256 + tid;
  int v = (g < NN) ? cnt[g] : 0;
  s[tid] = v;
  __syncthreads();
#pragma unroll
  for (int o = 1; o < 256; o <<= 1) {
    int t = (tid >= o) ? s[tid - o] : 0;
    __syncthreads();
    s[tid] += t;
    __syncthreads();
  }
  if (g < NN) base[g] = s[tid] - v;
  if (tid == 255) bsum[blockIdx.x] = s[255];
}

__global__ __launch_bounds__(256) void scan2(int* __restrict__ bsum, int nb) {
  __shared__ int s[256];
  const int tid = threadIdx.x;
  int v = (tid < nb) ? bsum[tid] : 0;
  s[tid] = v;
  __syncthreads();
#pragma unroll
  for (int o = 1; o < 256; o <<= 1) {
    int t = (tid >= o) ? s[tid - o] : 0;
    __syncthreads();
    s[tid] += t;
    __syncthreads();
  }
  if (tid < nb) bsum[tid] = s[tid] - v;
}

__global__ __launch_bounds__(256) void scan3(
    int* __restrict__ base, const int* __restrict__ bsum, int* __restrict__ off) {
  int g = blockIdx.x * 256 + threadIdx.x;
  if (g < NN) {
    int b = base[g] + bsum[g >> 8];
    base[g] = b;
    off[g] = b;
  } else if (g == NN) {
    base[NN] = NE;
  }
}

// Also emits position-sorted src/dst arrays so the edge kernel needs no
// ei indirection.
__global__ __launch_bounds__(256) void slot_kernel(
    const int* __restrict__ ei, int* __restrict__ off, int* __restrict__ perm,
    int* __restrict__ src2, int* __restrict__ dst2) {
  int e = blockIdx.x * 256 + threadIdx.x;
  if (e < NE) {
    const int d = ei[NE + e];
    int p = atomicAdd(&off[d], 1);
    perm[p] = e;
    src2[p] = ei[e];
    dst2[p] = d;
  }
}

// ================= edge kernel: MLP layer-1 + direct aggregation =========
// Block = 64 consecutive CSR positions. Computes relu([x|ea]@W1a + b1a)
// (256-d hidden) and accumulates per-dst column sums straight into
// sumbuf[NN][256] fp32. CSR ordering => same-dst rows are contiguous runs;
// one flush per run per column. Exclusive runs use plain stores, boundary
// runs atomicAdd.
__global__ __launch_bounds__(256) void edge_agg(
    const float* __restrict__ x, const float* __restrict__ ea,
    const int* __restrict__ perm, const int* __restrict__ src2,
    const int* __restrict__ dst2, const int* __restrict__ base,
    const bf16_t* __restrict__ Wt1a, const float* __restrict__ b1a,
    float* __restrict__ sumbuf) {
  __shared__ __align__(16) bf16_t Ain[64][264];
  __shared__ int srcS[64], dstS[64], eS[64];
  const int tid = threadIdx.x, lane = tid & 63, wave = tid >> 6;
  const int g0 = blockIdx.x * 64;

  if (tid < 64) {
    srcS[tid] = src2[g0 + tid];
    dstS[tid] = dst2[g0 + tid];
    eS[tid] = perm[g0 + tid];
  }
  __syncthreads();

  // stage concat [x[src] | ea[e]] -> Ain bf16 (K=256)
  {
    const int c0 = (tid & 63) * 4;
    const int esub = tid >> 6;
#pragma unroll
    for (int it = 0; it < 16; ++it) {
      const int i = it * 4 + esub;
      float4 f;
      if (c0 < 128)
        f = *(const float4*)(x + (size_t)srcS[i] * 128 + c0);
      else
        f = *(const float4*)(ea + (size_t)eS[i] * 128 + (c0 - 128));
      union { bf16_t h[4]; uint2 u2; } pk;
      pk.h[0] = (bf16_t)f.x; pk.h[1] = (bf16_t)f.y;
      pk.h[2] = (bf16_t)f.z; pk.h[3] = (bf16_t)f.w;
      *(uint2*)&Ain[i][c0] = pk.u2;
    }
  }
  __syncthreads();

  const int lr = lane & 15, lq = lane >> 4;
  const int n_off = wave * 64;
  float bias1[4];
#pragma unroll
  for (int nt = 0; nt < 4; ++nt) bias1[nt] = b1a[n_off + nt * 16 + lr];

  f32x4 acc[4][4];
#pragma unroll
  for (int mt = 0; mt < 4; ++mt)
#pragma unroll
    for (int nt = 0; nt < 4; ++nt) acc[mt][nt] = (f32x4){0.f, 0.f, 0.f, 0.f};
#pragma unroll
  for (int ks = 0; ks < 8; ++ks) {
    const int k0 = ks * 32 + lq * 8;
    bf16x8 af[4], bv[4];
#pragma unroll
    for (int mt = 0; mt < 4; ++mt) af[mt] = *(const bf16x8*)&Ain[mt * 16 + lr][k0];
#pragma unroll
    for (int nt = 0; nt < 4; ++nt)
      bv[nt] = *(const bf16x8*)&Wt1a[(n_off + nt * 16 + lr) * 256 + k0];
#pragma unroll
    for (int mt = 0; mt < 4; ++mt)
#pragma unroll
      for (int nt = 0; nt < 4; ++nt)
        acc[mt][nt] = __builtin_amdgcn_mfma_f32_16x16x32_bf16(
            af[mt], bv[nt], acc[mt][nt], 0, 0, 0);
  }
  __syncthreads();  // Ain reads complete

  // scatter relu(Q + b1a) bf16 -> Ain[64][0..255]
#pragma unroll
  for (int mt = 0; mt < 4; ++mt)
#pragma unroll
    for (int nt = 0; nt < 4; ++nt) {
      const int row = mt * 16 + lq * 4;
      const int colF = n_off + nt * 16 + lr;
#pragma unroll
      for (int r = 0; r < 4; ++r)
        Ain[row + r][colF] = (bf16_t)fmaxf(acc[mt][nt][r] + bias1[nt], 0.f);
    }
  __syncthreads();

  // column reduction with per-run flush (thread owns column c = tid)
  const int c = tid;
  float s = 0.f;
  int cur = dstS[0];
  for (int j = 0; j < 64; ++j) {
    const int d = dstS[j];
    if (d != cur) {
      if (base[cur] >= g0 && base[cur + 1] <= g0 + 64)
        sumbuf[(size_t)cur * 256 + c] = s;
      else
        atomicAdd(&sumbuf[(size_t)cur * 256 + c], s);
      s = 0.f;
      cur = d;
    }
    s += (float)Ain[j][c];
  }
  if (base[cur] >= g0 && base[cur + 1] <= g0 + 64)
    sumbuf[(size_t)cur * 256 + c] = s;
  else
    atomicAdd(&sumbuf[(size_t)cur * 256 + c], s);
}

// ================= node kernel: mean -> @W1b -> mlp2 =================
__global__ __launch_bounds__(256) void node_kernel(
    const float* __restrict__ x, const float* __restrict__ u,
    const int* __restrict__ batch,
    const bf16_t* __restrict__ Wt1b, const float* __restrict__ b1b,
    const bf16_t* __restrict__ Wt2a, const float* __restrict__ b2a,
    const bf16_t* __restrict__ Wt2b, const float* __restrict__ b2b,
    const float* __restrict__ sumbuf, const int* __restrict__ base,
    float* __restrict__ out) {
  __shared__ __align__(16) bf16_t As[64][392];
  __shared__ int bS[64], bE[64];
  const int tid = threadIdx.x, lane = tid & 63, wave = tid >> 6;
  const int n0 = blockIdx.x * 64;

  if (tid < 64) {
    int n = n0 + tid;
    bS[tid] = (n < NN) ? base[n] : 0;
    bE[tid] = (n < NN) ? base[n + 1] : 0;
  }
  __syncthreads();

  // phase 1: A1 = sumbuf/cnt -> As cols 0..255 (streaming fp32 read)
  for (int v = tid; v < 64 * 64; v += 256) {
    const int i = v >> 6, c0 = (v & 63) * 4;
    const int n = n0 + i;
    float4 f = make_float4(0.f, 0.f, 0.f, 0.f);
    if (n < NN) f = *(const float4*)(sumbuf + (size_t)n * 256 + c0);
    const float inv = 1.0f / fmaxf((float)(bE[i] - bS[i]), 1.0f);
    union { bf16_t h[4]; uint2 uu; } pk;
    pk.h[0] = (bf16_t)(f.x * inv);
    pk.h[1] = (bf16_t)(f.y * inv);
    pk.h[2] = (bf16_t)(f.z * inv);
    pk.h[3] = (bf16_t)(f.w * inv);
    *(uint2*)&As[i][c0] = pk.uu;
  }
  __syncthreads();

  const int lr = lane & 15, lq = lane >> 4;

  // phase 2: agg = A1 @ W1b + b1b*[cnt>0] ; wave owns 32 cols of N=128
  const int n2 = wave * 32;
  float bias1b[2];
#pragma unroll
  for (int nt = 0; nt < 2; ++nt) bias1b[nt] = b1b[n2 + nt * 16 + lr];

  f32x4 accB[4][2];
#pragma unroll
  for (int mt = 0; mt < 4; ++mt)
#pragma unroll
    for (int nt = 0; nt < 2; ++nt) accB[mt][nt] = (f32x4){0.f, 0.f, 0.f, 0.f};

#pragma unroll
  for (int ks = 0; ks < 8; ++ks) {
    const int k0 = ks * 32 + lq * 8;
    bf16x8 af[4], bv[2];
#pragma unroll
    for (int mt = 0; mt < 4; ++mt) af[mt] = *(const bf16x8*)&As[mt * 16 + lr][k0];
#pragma unroll
    for (int nt = 0; nt < 2; ++nt)
      bv[nt] = *(const bf16x8*)&Wt1b[(n2 + nt * 16 + lr) * 256 + k0];
#pragma unroll
    for (int mt = 0; mt < 4; ++mt)
#pragma unroll
      for (int nt = 0; nt < 2; ++nt)
        accB[mt][nt] = __builtin_amdgcn_mfma_f32_16x16x32_bf16(
            af[mt], bv[nt], accB[mt][nt], 0, 0, 0);
  }
  __syncthreads();  // all A1 reads done before As is overwritten

  // write agg -> As cols 128..255 (conditional bias for empty buckets)
#pragma unroll
  for (int mt = 0; mt < 4; ++mt)
#pragma unroll
    for (int nt = 0; nt < 2; ++nt) {
      const int colF = n2 + nt * 16 + lr;
#pragma unroll
      for (int r = 0; r < 4; ++r) {
        const int row = mt * 16 + lq * 4 + r;
        const float bb = (bE[row] > bS[row]) ? bias1b[nt] : 0.f;
        As[row][128 + colF] = (bf16_t)(accB[mt][nt][r] + bb);
      }
    }
  // stage x (cols 0..127) and u[batch] (cols 256..383)
  for (int v = tid; v < 64 * 32; v += 256) {
    const int i = v >> 5, c0 = (v & 31) * 4;
    const int n = n0 + i;
    float4 f = make_float4(0.f, 0.f, 0.f, 0.f);
    if (n < NN) f = *(const float4*)(x + (size_t)n * 128 + c0);
    union { bf16_t h[4]; uint2 uu; } pk;
    pk.h[0] = (bf16_t)f.x; pk.h[1] = (bf16_t)f.y;
    pk.h[2] = (bf16_t)f.z; pk.h[3] = (bf16_t)f.w;
    *(uint2*)&As[i][c0] = pk.uu;
  }
  for (int v = tid; v < 64 * 32; v += 256) {
    const int i = v >> 5, c0 = (v & 31) * 4;
    const int n = n0 + i;
    float4 f = make_float4(0.f, 0.f, 0.f, 0.f);
    if (n < NN) f = *(const float4*)(u + (size_t)batch[n] * 128 + c0);
    union { bf16_t h[4]; uint2 uu; } pk;
    pk.h[0] = (bf16_t)f.x; pk.h[1] = (bf16_t)f.y;
    pk.h[2] = (bf16_t)f.z; pk.h[3] = (bf16_t)f.w;
    *(uint2*)&As[i][256 + c0] = pk.uu;
  }
  __syncthreads();

  // phase 3: mlp2 layer 1: hidden(64x256) = relu(z @ W2a + b2a)
  const int n_off = wave * 64;
  float bias1[4];
#pragma unroll
  for (int nt = 0; nt < 4; ++nt) bias1[nt] = b2a[n_off + nt * 16 + lr];

  f32x4 acc[4][4];
#pragma unroll
  for (int mt = 0; mt < 4; ++mt)
#pragma unroll
    for (int nt = 0; nt < 4; ++nt) acc[mt][nt] = (f32x4){0.f, 0.f, 0.f, 0.f};

#pragma unroll
  for (int ks = 0; ks < 12; ++ks) {
    const int k0 = ks * 32 + lq * 8;
    bf16x8 af[4], bv[4];
#pragma unroll
    for (int mt = 0; mt < 4; ++mt) af[mt] = *(const bf16x8*)&As[mt * 16 + lr][k0];
#pragma unroll
    for (int nt = 0; nt < 4; ++nt)
      bv[nt] = *(const bf16x8*)&Wt2a[(n_off + nt * 16 + lr) * 384 + k0];
#pragma unroll
    for (int mt = 0; mt < 4; ++mt)
#pragma unroll
      for (int nt = 0; nt < 4; ++nt)
        acc[mt][nt] = __builtin_amdgcn_mfma_f32_16x16x32_bf16(
            af[mt], bv[nt], acc[mt][nt], 0, 0, 0);
  }
  __syncthreads();
#pragma unroll
  for (int mt = 0; mt < 4; ++mt)
#pragma unroll
    for (int nt = 0; nt < 4; ++nt) {
      const int row = mt * 16 + lq * 4;
      const int colF = n_off + nt * 16 + lr;
#pragma unroll
      for (int r = 0; r < 4; ++r) {
        float v = acc[mt][nt][r] + bias1[nt];
        As[row + r][colF] = (bf16_t)fmaxf(v, 0.f);
      }
    }
  __syncthreads();

  // mlp2 layer 2: out(64x128) = hidden @ W2b + b2b
  float bias2[2];
#pragma unroll
  for (int nt = 0; nt < 2; ++nt) bias2[nt] = b2b[n2 + nt * 16 + lr];

  f32x4 acc2[4][2];
#pragma unroll
  for (int mt = 0; mt < 4; ++mt)
#pragma unroll
    for (int nt = 0; nt < 2; ++nt) acc2[mt][nt] = (f32x4){0.f, 0.f, 0.f, 0.f};

#pragma unroll
  for (int ks = 0; ks < 8; ++ks) {
    const int k0 = ks * 32 + lq * 8;
    bf16x8 af[4], bv[2];
#pragma unroll
    for (int mt = 0; mt < 4; ++mt) af[mt] = *(const bf16x8*)&As[mt * 16 + lr][k0];
#pragma unroll
    for (int nt = 0; nt < 2; ++nt)
      bv[nt] = *(const bf16x8*)&Wt2b[(n2 + nt * 16 + lr) * 256 + k0];
#pragma unroll
    for (int mt = 0; mt < 4; ++mt)
#pragma unroll
      for (int nt = 0; nt < 2; ++nt)
        acc2[mt][nt] = __builtin_amdgcn_mfma_f32_16x16x32_bf16(
            af[mt], bv[nt], acc2[mt][nt], 0, 0, 0);
  }

#pragma unroll
  for (int mt = 0; mt < 4; ++mt)
#pragma unroll
    for (int nt = 0; nt < 2; ++nt) {
      const int colF = n2 + nt * 16 + lr;
#pragma unroll
      for (int r = 0; r < 4; ++r) {
        const int row = mt * 16 + lq * 4 + r;
        const int n = n0 + row;
        if (n < NN) out[(size_t)n * 128 + colF] = acc2[mt][nt][r] + bias2[nt];
      }
    }
}

extern "C" void kernel_launch(void* const* d_in, const int* in_sizes, int n_in,
                              void* d_out, int out_size, void* d_ws, size_t ws_size,
                              hipStream_t stream) {
  const float* x    = (const float*)d_in[0];
  const int*   ei   = (const int*)d_in[1];
  const float* ea   = (const float*)d_in[2];
  const float* u    = (const float*)d_in[3];
  const int*   batch= (const int*)d_in[4];
  const float* W1a  = (const float*)d_in[5];
  const float* b1a  = (const float*)d_in[6];
  const float* W1b  = (const float*)d_in[7];
  const float* b1b  = (const float*)d_in[8];
  const float* W2a  = (const float*)d_in[9];
  const float* b2a  = (const float*)d_in[10];
  const float* W2b  = (const float*)d_in[11];
  const float* b2b  = (const float*)d_in[12];

  char* ws = (char*)d_ws;
  bf16_t* w1a = (bf16_t*)(ws + W1A_OFF);
  bf16_t* w1b = (bf16_t*)(ws + W1B_OFF);
  bf16_t* w2a = (bf16_t*)(ws + W2A_OFF);
  bf16_t* w2b = (bf16_t*)(ws + W2B_OFF);

  transpose_bf16<<<256, 256, 0, stream>>>(W1a, w1a, 256, 256);
  transpose_bf16<<<128, 256, 0, stream>>>(W1b, w1b, 256, 128);
  transpose_bf16<<<384, 256, 0, stream>>>(W2a, w2a, 384, 256);
  transpose_bf16<<<128, 256, 0, stream>>>(W2b, w2b, 256, 128);

  int* base = (int*)(ws + BASE_OFF);
  int* bsum = (int*)(ws + BSUM_OFF);
  int* off  = (int*)(ws + OFF_OFF);
  int* cnt  = (int*)(ws + CNT2_OFF);
  int* perm = (int*)(ws + PERM_OFF);
  int* src2 = (int*)(ws + SRC2_OFF);
  int* dst2 = (int*)(ws + DST2_OFF);
  float* sumbuf = (float*)(ws + SUM_OFF);

  hipMemsetAsync(cnt, 0, CNT2_B, stream);
  hipMemsetAsync(sumbuf, 0, SUM_B, stream);
  hist_kernel<<<(NE + 255) / 256, 256, 0, stream>>>(ei, cnt);
  scan1<<<NSCAN_BLOCKS, 256, 0, stream>>>(cnt, base, bsum);
  scan2<<<1, 256, 0, stream>>>(bsum, NSCAN_BLOCKS);
  scan3<<<(NN + 256) / 256, 256, 0, stream>>>(base, bsum, off);
  slot_kernel<<<(NE + 255) / 256, 256, 0, stream>>>(ei, off, perm, src2, dst2);

  edge_agg<<<NE / 64, 256, 0, stream>>>(
      x, ea, perm, src2, dst2, base, w1a, b1a, sumbuf);
  node_kernel<<<(NN + 63) / 64, 256, 0, stream>>>(
      x, u, batch, w1b, b1b, w2a, b2a, w2b, b2b, sumbuf, base,
      (float*)d_out);
}

// Round 4
// 1059.163 us; speedup vs baseline: 1.4010x; 1.0460x over previous
//
#include <hip/hip_runtime.h>

#define NN 50000
#define NE 800000

typedef __bf16 bf16_t;
typedef __bf16 bf16x8 __attribute__((ext_vector_type(8)));
typedef float f32x4 __attribute__((ext_vector_type(4)));

// ---- workspace layout (bytes) ----
#define W1A_OFF 0
#define W1A_B (256 * 256 * 2)
#define W1B_OFF (W1A_OFF + W1A_B)
#define W1B_B (128 * 256 * 2)
#define W2A_OFF (W1B_OFF + W1B_B)
#define W2A_B (256 * 384 * 2)
#define W2B_OFF (W2A_OFF + W2A_B)
#define W2B_B (128 * 256 * 2)
#define WEND (W2B_OFF + W2B_B)

#define NSCAN_BLOCKS ((NN + 255) / 256)
#define BASE_OFF WEND
#define BASE_B (((NN + 1 + 63) / 64) * 64 * 4)
#define BSUM_OFF (BASE_OFF + BASE_B)
#define BSUM_B (256 * 4)
#define OFF_OFF (BSUM_OFF + BSUM_B)
#define OFF_B (NN * 4)
#define CNT2_OFF (OFF_OFF + OFF_B)
#define CNT2_B (NN * 4)
#define PERM_OFF (CNT2_OFF + CNT2_B)
#define PERM_B (NE * 4)
#define DST2_OFF (PERM_OFF + PERM_B)
#define DST2_B (NE * 4)
#define SUM_OFF ((size_t)(((DST2_OFF + DST2_B) + 255) / 256 * 256))
#define SUM_B ((size_t)NN * 256 * 4)

// Convert W[k][n] (row-major fp32) -> Wt[n][k] bf16 (k contiguous).
__global__ __launch_bounds__(256) void transpose_bf16(
    const float* __restrict__ src, bf16_t* __restrict__ dst, int K, int Nn) {
  int idx = blockIdx.x * 256 + threadIdx.x;
  if (idx >= K * Nn) return;
  int n = idx / K;
  int k = idx - n * K;
  dst[idx] = (bf16_t)src[k * Nn + n];
}

// ================= CSR construction =================
__global__ __launch_bounds__(256) void hist_kernel(
    const int* __restrict__ ei, int* __restrict__ cnt) {
  int e = blockIdx.x * 256 + threadIdx.x;
  if (e < NE) atomicAdd(&cnt[ei[NE + e]], 1);
}

__global__ __launch_bounds__(256) void scan1(
    const int* __restrict__ cnt, int* __restrict__ base, int* __restrict__ bsum) {
  __shared__ int s[256];
  const int tid = threadIdx.x;
  const int g = blockIdx.x * 256 + tid;
  int v = (g < NN) ? cnt[g] : 0;
  s[tid] = v;
  __syncthreads();
#pragma unroll
  for (int o = 1; o < 256; o <<= 1) {
    int t = (tid >= o) ? s[tid - o] : 0;
    __syncthreads();
    s[tid] += t;
    __syncthreads();
  }
  if (g < NN) base[g] = s[tid] - v;
  if (tid == 255) bsum[blockIdx.x] = s[255];
}

__global__ __launch_bounds__(256) void scan2(int* __restrict__ bsum, int nb) {
  __shared__ int s[256];
  const int tid = threadIdx.x;
  int v = (tid < nb) ? bsum[tid] : 0;
  s[tid] = v;
  __syncthreads();
#pragma unroll
  for (int o = 1; o < 256; o <<= 1) {
    int t = (tid >= o) ? s[tid - o] : 0;
    __syncthreads();
    s[tid] += t;
    __syncthreads();
  }
  if (tid < nb) bsum[tid] = s[tid] - v;
}

__global__ __launch_bounds__(256) void scan3(
    int* __restrict__ base, const int* __restrict__ bsum, int* __restrict__ off) {
  int g = blockIdx.x * 256 + threadIdx.x;
  if (g < NN) {
    int b = base[g] + bsum[g >> 8];
    base[g] = b;
    off[g] = b;
  } else if (g == NN) {
    base[NN] = NE;
  }
}

__global__ __launch_bounds__(256) void slot_kernel(
    const int* __restrict__ ei, int* __restrict__ off, int* __restrict__ perm) {
  int e = blockIdx.x * 256 + threadIdx.x;
  if (e < NE) {
    int p = atomicAdd(&off[ei[NE + e]], 1);
    perm[p] = e;
  }
}

// Fill dst2[p] = n for p in [base[n], base[n+1]) -- sequential writes,
// replaces the scattered dst2 writes that bloated slot_kernel.
__global__ __launch_bounds__(256) void dst_fill(
    const int* __restrict__ base, int* __restrict__ dst2) {
  int n = blockIdx.x * 256 + threadIdx.x;
  if (n < NN) {
    const int b0 = base[n], b1 = base[n + 1];
    for (int j = b0; j < b1; ++j) dst2[j] = n;
  }
}

// ================= edge kernel: MLP layer-1 + direct aggregation =========
// Block = 32 consecutive CSR positions (small LDS -> ~8 blocks/CU for
// latency hiding). relu([x[src]|ea[e]]@W1a + b1a) -> per-run column sums
// into sumbuf[NN][256]. Runs touching block boundary -> atomicAdd (no
// global loads needed); interior runs are complete -> plain store.
__global__ __launch_bounds__(256) void edge_agg(
    const float* __restrict__ x, const float* __restrict__ ea,
    const int* __restrict__ ei, const int* __restrict__ perm,
    const int* __restrict__ dst2,
    const bf16_t* __restrict__ Wt1a, const float* __restrict__ b1a,
    float* __restrict__ sumbuf) {
  __shared__ __align__(16) bf16_t Ain[32][264];
  __shared__ int srcS[32], dstS[32], eS[32];
  const int tid = threadIdx.x, lane = tid & 63, wave = tid >> 6;
  const int g0 = blockIdx.x * 32;

  if (tid < 32) {
    const int e = perm[g0 + tid];
    eS[tid] = e;
    dstS[tid] = dst2[g0 + tid];
    srcS[tid] = ei[e];
  }
  __syncthreads();

  // stage ea[e] -> cols 128..255 (each row = full 512B segment, coalesced)
#pragma unroll
  for (int k = 0; k < 4; ++k) {
    const int v = tid + k * 256;
    const int i = v >> 5, c0 = (v & 31) * 4;
    float4 f = *(const float4*)(ea + (size_t)eS[i] * 128 + c0);
    union { bf16_t h[4]; uint2 u2; } pk;
    pk.h[0] = (bf16_t)f.x; pk.h[1] = (bf16_t)f.y;
    pk.h[2] = (bf16_t)f.z; pk.h[3] = (bf16_t)f.w;
    *(uint2*)&Ain[i][128 + c0] = pk.u2;
  }
  // stage x[src] -> cols 0..127
#pragma unroll
  for (int k = 0; k < 4; ++k) {
    const int v = tid + k * 256;
    const int i = v >> 5, c0 = (v & 31) * 4;
    float4 f = *(const float4*)(x + (size_t)srcS[i] * 128 + c0);
    union { bf16_t h[4]; uint2 u2; } pk;
    pk.h[0] = (bf16_t)f.x; pk.h[1] = (bf16_t)f.y;
    pk.h[2] = (bf16_t)f.z; pk.h[3] = (bf16_t)f.w;
    *(uint2*)&Ain[i][c0] = pk.u2;
  }
  __syncthreads();

  const int lr = lane & 15, lq = lane >> 4;
  const int n_off = wave * 64;
  float bias1[4];
#pragma unroll
  for (int nt = 0; nt < 4; ++nt) bias1[nt] = b1a[n_off + nt * 16 + lr];

  // M=32, N=256 (wave owns 64 cols), K=256
  f32x4 acc[2][4];
#pragma unroll
  for (int mt = 0; mt < 2; ++mt)
#pragma unroll
    for (int nt = 0; nt < 4; ++nt) acc[mt][nt] = (f32x4){0.f, 0.f, 0.f, 0.f};
#pragma unroll
  for (int ks = 0; ks < 8; ++ks) {
    const int k0 = ks * 32 + lq * 8;
    bf16x8 af[2], bv[4];
#pragma unroll
    for (int mt = 0; mt < 2; ++mt) af[mt] = *(const bf16x8*)&Ain[mt * 16 + lr][k0];
#pragma unroll
    for (int nt = 0; nt < 4; ++nt)
      bv[nt] = *(const bf16x8*)&Wt1a[(n_off + nt * 16 + lr) * 256 + k0];
#pragma unroll
    for (int mt = 0; mt < 2; ++mt)
#pragma unroll
      for (int nt = 0; nt < 4; ++nt)
        acc[mt][nt] = __builtin_amdgcn_mfma_f32_16x16x32_bf16(
            af[mt], bv[nt], acc[mt][nt], 0, 0, 0);
  }
  __syncthreads();  // Ain reads complete

  // scatter relu(Q + b1a) bf16 -> Ain[32][0..255]
#pragma unroll
  for (int mt = 0; mt < 2; ++mt)
#pragma unroll
    for (int nt = 0; nt < 4; ++nt) {
      const int row = mt * 16 + lq * 4;
      const int colF = n_off + nt * 16 + lr;
#pragma unroll
      for (int r = 0; r < 4; ++r)
        Ain[row + r][colF] = (bf16_t)fmaxf(acc[mt][nt][r] + bias1[nt], 0.f);
    }
  __syncthreads();

  // per-run column reduction; wave-uniform control flow, no global loads
  const int c = tid;
  float s = 0.f;
  int cur = dstS[0];
  bool bnd = true;  // current run touches block start?
  for (int j = 0; j < 32; ++j) {
    const int d = dstS[j];
    if (d != cur) {
      if (bnd)
        atomicAdd(&sumbuf[(size_t)cur * 256 + c], s);
      else
        sumbuf[(size_t)cur * 256 + c] = s;
      s = 0.f;
      cur = d;
      bnd = false;
    }
    s += (float)Ain[j][c];
  }
  // last run touches block end -> always atomic
  atomicAdd(&sumbuf[(size_t)cur * 256 + c], s);
}

// ================= node kernel: mean -> @W1b -> mlp2 =================
__global__ __launch_bounds__(256) void node_kernel(
    const float* __restrict__ x, const float* __restrict__ u,
    const int* __restrict__ batch,
    const bf16_t* __restrict__ Wt1b, const float* __restrict__ b1b,
    const bf16_t* __restrict__ Wt2a, const float* __restrict__ b2a,
    const bf16_t* __restrict__ Wt2b, const float* __restrict__ b2b,
    const float* __restrict__ sumbuf, const int* __restrict__ base,
    float* __restrict__ out) {
  __shared__ __align__(16) bf16_t As[64][392];
  __shared__ int bS[64], bE[64];
  const int tid = threadIdx.x, lane = tid & 63, wave = tid >> 6;
  const int n0 = blockIdx.x * 64;

  if (tid < 64) {
    int n = n0 + tid;
    bS[tid] = (n < NN) ? base[n] : 0;
    bE[tid] = (n < NN) ? base[n + 1] : 0;
  }
  __syncthreads();

  // phase 1: A1 = sumbuf/cnt -> As cols 0..255 (streaming fp32 read)
  for (int v = tid; v < 64 * 64; v += 256) {
    const int i = v >> 6, c0 = (v & 63) * 4;
    const int n = n0 + i;
    float4 f = make_float4(0.f, 0.f, 0.f, 0.f);
    if (n < NN) f = *(const float4*)(sumbuf + (size_t)n * 256 + c0);
    const float inv = 1.0f / fmaxf((float)(bE[i] - bS[i]), 1.0f);
    union { bf16_t h[4]; uint2 uu; } pk;
    pk.h[0] = (bf16_t)(f.x * inv);
    pk.h[1] = (bf16_t)(f.y * inv);
    pk.h[2] = (bf16_t)(f.z * inv);
    pk.h[3] = (bf16_t)(f.w * inv);
    *(uint2*)&As[i][c0] = pk.uu;
  }
  __syncthreads();

  const int lr = lane & 15, lq = lane >> 4;

  // phase 2: agg = A1 @ W1b + b1b*[cnt>0] ; wave owns 32 cols of N=128
  const int n2 = wave * 32;
  float bias1b[2];
#pragma unroll
  for (int nt = 0; nt < 2; ++nt) bias1b[nt] = b1b[n2 + nt * 16 + lr];

  f32x4 accB[4][2];
#pragma unroll
  for (int mt = 0; mt < 4; ++mt)
#pragma unroll
    for (int nt = 0; nt < 2; ++nt) accB[mt][nt] = (f32x4){0.f, 0.f, 0.f, 0.f};

#pragma unroll
  for (int ks = 0; ks < 8; ++ks) {
    const int k0 = ks * 32 + lq * 8;
    bf16x8 af[4], bv[2];
#pragma unroll
    for (int mt = 0; mt < 4; ++mt) af[mt] = *(const bf16x8*)&As[mt * 16 + lr][k0];
#pragma unroll
    for (int nt = 0; nt < 2; ++nt)
      bv[nt] = *(const bf16x8*)&Wt1b[(n2 + nt * 16 + lr) * 256 + k0];
#pragma unroll
    for (int mt = 0; mt < 4; ++mt)
#pragma unroll
      for (int nt = 0; nt < 2; ++nt)
        accB[mt][nt] = __builtin_amdgcn_mfma_f32_16x16x32_bf16(
            af[mt], bv[nt], accB[mt][nt], 0, 0, 0);
  }
  __syncthreads();  // all A1 reads done before As is overwritten

  // write agg -> As cols 128..255 (conditional bias for empty buckets)
#pragma unroll
  for (int mt = 0; mt < 4; ++mt)
#pragma unroll
    for (int nt = 0; nt < 2; ++nt) {
      const int colF = n2 + nt * 16 + lr;
#pragma unroll
      for (int r = 0; r < 4; ++r) {
        const int row = mt * 16 + lq * 4 + r;
        const float bb = (bE[row] > bS[row]) ? bias1b[nt] : 0.f;
        As[row][128 + colF] = (bf16_t)(accB[mt][nt][r] + bb);
      }
    }
  // stage x (cols 0..127) and u[batch] (cols 256..383)
  for (int v = tid; v < 64 * 32; v += 256) {
    const int i = v >> 5, c0 = (v & 31) * 4;
    const int n = n0 + i;
    float4 f = make_float4(0.f, 0.f, 0.f, 0.f);
    if (n < NN) f = *(const float4*)(x + (size_t)n * 128 + c0);
    union { bf16_t h[4]; uint2 uu; } pk;
    pk.h[0] = (bf16_t)f.x; pk.h[1] = (bf16_t)f.y;
    pk.h[2] = (bf16_t)f.z; pk.h[3] = (bf16_t)f.w;
    *(uint2*)&As[i][c0] = pk.uu;
  }
  for (int v = tid; v < 64 * 32; v += 256) {
    const int i = v >> 5, c0 = (v & 31) * 4;
    const int n = n0 + i;
    float4 f = make_float4(0.f, 0.f, 0.f, 0.f);
    if (n < NN) f = *(const float4*)(u + (size_t)batch[n] * 128 + c0);
    union { bf16_t h[4]; uint2 uu; } pk;
    pk.h[0] = (bf16_t)f.x; pk.h[1] = (bf16_t)f.y;
    pk.h[2] = (bf16_t)f.z; pk.h[3] = (bf16_t)f.w;
    *(uint2*)&As[i][256 + c0] = pk.uu;
  }
  __syncthreads();

  // phase 3: mlp2 layer 1: hidden(64x256) = relu(z @ W2a + b2a)
  const int n_off = wave * 64;
  float bias1[4];
#pragma unroll
  for (int nt = 0; nt < 4; ++nt) bias1[nt] = b2a[n_off + nt * 16 + lr];

  f32x4 acc[4][4];
#pragma unroll
  for (int mt = 0; mt < 4; ++mt)
#pragma unroll
    for (int nt = 0; nt < 4; ++nt) acc[mt][nt] = (f32x4){0.f, 0.f, 0.f, 0.f};

#pragma unroll
  for (int ks = 0; ks < 12; ++ks) {
    const int k0 = ks * 32 + lq * 8;
    bf16x8 af[4], bv[4];
#pragma unroll
    for (int mt = 0; mt < 4; ++mt) af[mt] = *(const bf16x8*)&As[mt * 16 + lr][k0];
#pragma unroll
    for (int nt = 0; nt < 4; ++nt)
      bv[nt] = *(const bf16x8*)&Wt2a[(n_off + nt * 16 + lr) * 384 + k0];
#pragma unroll
    for (int mt = 0; mt < 4; ++mt)
#pragma unroll
      for (int nt = 0; nt < 4; ++nt)
        acc[mt][nt] = __builtin_amdgcn_mfma_f32_16x16x32_bf16(
            af[mt], bv[nt], acc[mt][nt], 0, 0, 0);
  }
  __syncthreads();
#pragma unroll
  for (int mt = 0; mt < 4; ++mt)
#pragma unroll
    for (int nt = 0; nt < 4; ++nt) {
      const int row = mt * 16 + lq * 4;
      const int colF = n_off + nt * 16 + lr;
#pragma unroll
      for (int r = 0; r < 4; ++r) {
        float v = acc[mt][nt][r] + bias1[nt];
        As[row + r][colF] = (bf16_t)fmaxf(v, 0.f);
      }
    }
  __syncthreads();

  // mlp2 layer 2: out(64x128) = hidden @ W2b + b2b
  float bias2[2];
#pragma unroll
  for (int nt = 0; nt < 2; ++nt) bias2[nt] = b2b[n2 + nt * 16 + lr];

  f32x4 acc2[4][2];
#pragma unroll
  for (int mt = 0; mt < 4; ++mt)
#pragma unroll
    for (int nt = 0; nt < 2; ++nt) acc2[mt][nt] = (f32x4){0.f, 0.f, 0.f, 0.f};

#pragma unroll
  for (int ks = 0; ks < 8; ++ks) {
    const int k0 = ks * 32 + lq * 8;
    bf16x8 af[4], bv[2];
#pragma unroll
    for (int mt = 0; mt < 4; ++mt) af[mt] = *(const bf16x8*)&As[mt * 16 + lr][k0];
#pragma unroll
    for (int nt = 0; nt < 2; ++nt)
      bv[nt] = *(const bf16x8*)&Wt2b[(n2 + nt * 16 + lr) * 256 + k0];
#pragma unroll
    for (int mt = 0; mt < 4; ++mt)
#pragma unroll
      for (int nt = 0; nt < 2; ++nt)
        acc2[mt][nt] = __builtin_amdgcn_mfma_f32_16x16x32_bf16(
            af[mt], bv[nt], acc2[mt][nt], 0, 0, 0);
  }

#pragma unroll
  for (int mt = 0; mt < 4; ++mt)
#pragma unroll
    for (int nt = 0; nt < 2; ++nt) {
      const int colF = n2 + nt * 16 + lr;
#pragma unroll
      for (int r = 0; r < 4; ++r) {
        const int row = mt * 16 + lq * 4 + r;
        const int n = n0 + row;
        if (n < NN) out[(size_t)n * 128 + colF] = acc2[mt][nt][r] + bias2[nt];
      }
    }
}

extern "C" void kernel_launch(void* const* d_in, const int* in_sizes, int n_in,
                              void* d_out, int out_size, void* d_ws, size_t ws_size,
                              hipStream_t stream) {
  const float* x    = (const float*)d_in[0];
  const int*   ei   = (const int*)d_in[1];
  const float* ea   = (const float*)d_in[2];
  const float* u    = (const float*)d_in[3];
  const int*   batch= (const int*)d_in[4];
  const float* W1a  = (const float*)d_in[5];
  const float* b1a  = (const float*)d_in[6];
  const float* W1b  = (const float*)d_in[7];
  const float* b1b  = (const float*)d_in[8];
  const float* W2a  = (const float*)d_in[9];
  const float* b2a  = (const float*)d_in[10];
  const float* W2b  = (const float*)d_in[11];
  const float* b2b  = (const float*)d_in[12];

  char* ws = (char*)d_ws;
  bf16_t* w1a = (bf16_t*)(ws + W1A_OFF);
  bf16_t* w1b = (bf16_t*)(ws + W1B_OFF);
  bf16_t* w2a = (bf16_t*)(ws + W2A_OFF);
  bf16_t* w2b = (bf16_t*)(ws + W2B_OFF);

  transpose_bf16<<<256, 256, 0, stream>>>(W1a, w1a, 256, 256);
  transpose_bf16<<<128, 256, 0, stream>>>(W1b, w1b, 256, 128);
  transpose_bf16<<<384, 256, 0, stream>>>(W2a, w2a, 384, 256);
  transpose_bf16<<<128, 256, 0, stream>>>(W2b, w2b, 256, 128);

  int* base = (int*)(ws + BASE_OFF);
  int* bsum = (int*)(ws + BSUM_OFF);
  int* off  = (int*)(ws + OFF_OFF);
  int* cnt  = (int*)(ws + CNT2_OFF);
  int* perm = (int*)(ws + PERM_OFF);
  int* dst2 = (int*)(ws + DST2_OFF);
  float* sumbuf = (float*)(ws + SUM_OFF);

  hipMemsetAsync(cnt, 0, CNT2_B, stream);
  hipMemsetAsync(sumbuf, 0, SUM_B, stream);
  hist_kernel<<<(NE + 255) / 256, 256, 0, stream>>>(ei, cnt);
  scan1<<<NSCAN_BLOCKS, 256, 0, stream>>>(cnt, base, bsum);
  scan2<<<1, 256, 0, stream>>>(bsum, NSCAN_BLOCKS);
  scan3<<<(NN + 256) / 256, 256, 0, stream>>>(base, bsum, off);
  slot_kernel<<<(NE + 255) / 256, 256, 0, stream>>>(ei, off, perm);
  dst_fill<<<(NN + 255) / 256, 256, 0, stream>>>(base, dst2);

  edge_agg<<<NE / 32, 256, 0, stream>>>(
      x, ea, ei, perm, dst2, w1a, b1a, sumbuf);
  node_kernel<<<(NN + 63) / 64, 256, 0, stream>>>(
      x, u, batch, w1b, b1b, w2a, b2a, w2b, b2b, sumbuf, base,
      (float*)d_out);
}